// Round 10
// baseline (4209.916 us; speedup 1.0000x reference)
//
#include <hip/hip_runtime.h>
#include <math.h>

#define N_NODES 50000
#define N_EDGES 800000
#define D 128
#define E_DIM 16
#define DEPTH 3

typedef _Float16 half2_t __attribute__((ext_vector_type(2)));
typedef _Float16 half4_t __attribute__((ext_vector_type(4)));
typedef _Float16 half8_t __attribute__((ext_vector_type(8)));
typedef float floatx4 __attribute__((ext_vector_type(4)));

#if defined(__has_builtin)
#if __has_builtin(__builtin_amdgcn_fdot2)
#define FDOT2(a, b, c) __builtin_amdgcn_fdot2((a), (b), (c), false)
#endif
#endif
#ifndef FDOT2
static __device__ __forceinline__ float fdot2_sw(half2_t a, half2_t b, float c) {
    return fmaf((float)a.x, (float)b.x, fmaf((float)a.y, (float)b.y, c));
}
#define FDOT2(a, b, c) fdot2_sw((a), (b), (c))
#endif

// ------- prep: x f16 convert + MFMA weight packing + We packing + dst hist ---

#define NB_X   3125    // N_NODES*D/8/256
#define NB_W   384     // 6*16384/256
#define NB_WE  12      // 3*1024 half2 / 256
#define NB_H   3125    // N_EDGES/256
#define NB_PRE (NB_X + NB_W + NB_WE)

__global__ void k_prep(const float* __restrict__ x,
                       const float* __restrict__ W1, const float* __restrict__ W2,
                       const float* __restrict__ WeAll, const int* __restrict__ dst,
                       _Float16* __restrict__ xh,
                       _Float16* __restrict__ Wp, _Float16* __restrict__ Weh,
                       int* __restrict__ deg) {
    int b = blockIdx.x;
    if (b < NB_X) {
        int i = b * 256 + threadIdx.x;
        int base = i * 8;
        float4 a = *(const float4*)(x + base);
        float4 c = *(const float4*)(x + base + 4);
        half8_t h = {(_Float16)a.x, (_Float16)a.y, (_Float16)a.z, (_Float16)a.w,
                     (_Float16)c.x, (_Float16)c.y, (_Float16)c.z, (_Float16)c.w};
        *(half8_t*)(xh + base) = h;
    } else if (b < NB_X + NB_W) {
        int t = (b - NB_X) * 256 + threadIdx.x;
        int j    = t & 7;
        int lane = (t >> 3) & 63;
        int nb   = (t >> 9) & 7;
        int kb   = (t >> 12) & 3;
        int mat  = t >> 14;
        int layer = mat >> 1, which = mat & 1;
        const float* Wsrc = (which ? W2 : W1) + (size_t)layer * D * D;
        int k = kb * 32 + (lane >> 4) * 8 + j;
        int n = nb * 16 + (lane & 15);
        Wp[t] = (_Float16)Wsrc[k * D + n];
    } else if (b < NB_PRE) {
        // pack We as half2 pairs in k: layout [layer][c=0..31][kp=0..7][f=0..3]
        int t = (b - NB_X - NB_W) * 256 + threadIdx.x;  // 0..3071 (half2 index)
        int layer = t >> 10;
        int idx = t & 1023;
        int c = idx >> 5, kp = (idx >> 2) & 7, f = idx & 3;
        const float* Wsrc = WeAll + (size_t)layer * E_DIM * D;
        half2_t v = {(_Float16)Wsrc[(2 * kp) * D + 4 * c + f],
                     (_Float16)Wsrc[(2 * kp + 1) * D + 4 * c + f]};
        *(half2_t*)(Weh + 2 * (size_t)t) = v;
    } else {
        int e = (b - NB_PRE) * 256 + threadIdx.x;
        if (e < N_EDGES) atomicAdd(&deg[dst[e]], 1);
    }
}

// ---------------- mega kernel: scan + scatter + 3x(agg -> mlp) --------------
// Persistent grid: 1536 blocks = exactly 6/CU x 256 CU (launch_bounds(256,6)
// caps VGPR at 85 >= ~64 needed; LDS 17408 x 6 = 104KB < 160KB), so all
// blocks are co-resident and a device-scope atomic barrier is deadlock-free
// (r8's k_scan already validated cross-block spin on this chip). Each grid
// barrier replaces a kernel launch (~12us) at ~2-4us. Agg keeps the proven
// r6 persistent-wave structure (grid barrier == kernel boundary for
// imbalance purposes — unlike r8's block-level fusion).

#define GRID_BLOCKS 1536
#define GRID_THREADS (GRID_BLOCKS * 256)
#define AGG_WAVES  (GRID_BLOCKS * 4)              // 6144
#define AGG_Q      (N_NODES / AGG_WAVES)          // 8
#define AGG_R      (N_NODES - AGG_Q * AGG_WAVES)  // 848
#define SCAN_BLOCKS 49

__device__ __forceinline__ void gbar(unsigned* cnt, unsigned* flg, int idx) {
    __syncthreads();
    if (threadIdx.x == 0) {
        __threadfence();
        unsigned prev = __hip_atomic_fetch_add(&cnt[idx], 1u, __ATOMIC_ACQ_REL,
                                               __HIP_MEMORY_SCOPE_AGENT);
        if (prev + 1u == (unsigned)GRID_BLOCKS) {
            __hip_atomic_store(&flg[idx], 1u, __ATOMIC_RELEASE,
                               __HIP_MEMORY_SCOPE_AGENT);
        } else {
            while (__hip_atomic_load(&flg[idx], __ATOMIC_ACQUIRE,
                                     __HIP_MEMORY_SCOPE_AGENT) == 0u)
                __builtin_amdgcn_s_sleep(8);
        }
        __threadfence();
    }
    __syncthreads();
}

__global__ __launch_bounds__(256, 6) void k_mega(
    const int* __restrict__ deg, int* __restrict__ off, int* __restrict__ head,
    int* __restrict__ bsum, int* __restrict__ bflag,
    const int* __restrict__ src, const int* __restrict__ dst,
    int* __restrict__ sorted, const float* __restrict__ ea,
    _Float16* __restrict__ ea_s,
    _Float16* __restrict__ xb0, _Float16* __restrict__ xb1,
    _Float16* __restrict__ h0,
    const _Float16* __restrict__ Weh, const float* __restrict__ be,
    const float* __restrict__ eps,
    const _Float16* __restrict__ Wp, const float* __restrict__ b1,
    const float* __restrict__ b2, float* __restrict__ outf,
    unsigned* __restrict__ gcnt, unsigned* __restrict__ gflg) {
    __shared__ __align__(16) char smem[64 * 136 * 2];   // 17408 B, phase-reused
    int tid = threadIdx.x;
    int bid = blockIdx.x;

    // ===== phase 0: CSR scan (decoupled lookback, blocks 0..48) =====
    if (bid < SCAN_BLOCKS) {
        int* s = (int*)smem;
        int base = bid * 1024;
        int v[4]; int runv[4];
        int sum = 0;
#pragma unroll
        for (int j = 0; j < 4; j++) {
            int idx = base + tid * 4 + j;
            int xv = (idx < N_NODES) ? deg[idx] : 0;
            v[j] = xv; sum += xv;
        }
        s[tid] = sum;
        __syncthreads();
        for (int d2 = 1; d2 < 256; d2 <<= 1) {
            int val = (tid >= d2) ? s[tid - d2] : 0;
            __syncthreads();
            s[tid] += val;
            __syncthreads();
        }
        int run = (tid > 0) ? s[tid - 1] : 0;
#pragma unroll
        for (int j = 0; j < 4; j++) { run += v[j]; runv[j] = run; }
        if (tid == 0) {
            __hip_atomic_store(&bsum[bid], s[255], __ATOMIC_RELAXED,
                               __HIP_MEMORY_SCOPE_AGENT);
            __hip_atomic_store(&bflag[bid], 1, __ATOMIC_RELEASE,
                               __HIP_MEMORY_SCOPE_AGENT);
        }
        int p = 0;
        if (tid < bid) {
            while (__hip_atomic_load(&bflag[tid], __ATOMIC_ACQUIRE,
                                     __HIP_MEMORY_SCOPE_AGENT) == 0)
                __builtin_amdgcn_s_sleep(2);
            p = __hip_atomic_load(&bsum[tid], __ATOMIC_RELAXED,
                                  __HIP_MEMORY_SCOPE_AGENT);
        }
        __syncthreads();            // s[] reuse
        s[tid] = p;
        __syncthreads();
        for (int d2 = 128; d2 > 0; d2 >>= 1) {
            if (tid < d2) s[tid] += s[tid + d2];
            __syncthreads();
        }
        int prefix = s[0];
        if (bid == 0 && tid == 0) off[0] = 0;
#pragma unroll
        for (int j = 0; j < 4; j++) {
            int idx = base + tid * 4 + j;
            if (idx < N_NODES) {
                int incl = runv[j] + prefix;
                off[idx + 1] = incl;
                head[idx] = incl - v[j];   // exclusive prefix = scatter start
            }
        }
    }
    gbar(gcnt, gflg, 0);

    // ===== phase 1: scatter (edges dst-sorted; ea permuted + f16 convert) ===
    for (int e = bid * 256 + tid; e < N_EDGES; e += GRID_THREADS) {
        int d = dst[e];
        int pos = atomicAdd(&head[d], 1);
        sorted[pos] = src[e] << 8;
        const float* ep = ea + (size_t)e * E_DIM;
        float4 a = *(const float4*)(ep);
        float4 b = *(const float4*)(ep + 4);
        float4 c = *(const float4*)(ep + 8);
        float4 f = *(const float4*)(ep + 12);
        half8_t lo = {(_Float16)a.x, (_Float16)a.y, (_Float16)a.z, (_Float16)a.w,
                      (_Float16)b.x, (_Float16)b.y, (_Float16)b.z, (_Float16)b.w};
        half8_t hi = {(_Float16)c.x, (_Float16)c.y, (_Float16)c.z, (_Float16)c.w,
                      (_Float16)f.x, (_Float16)f.y, (_Float16)f.z, (_Float16)f.w};
        _Float16* op = ea_s + (size_t)pos * E_DIM;
        *(half8_t*)op = lo;
        *(half8_t*)(op + 8) = hi;
    }
    gbar(gcnt, gflg, 1);

    // ===== phases 2..: layers =====
    _Float16* xc = xb0;
    _Float16* xn = xb1;
    int barix = 2;
    for (int l = 0; l < DEPTH; l++) {
        // ---- agg (r6-proven structure, NO nontemporal: r9 lesson) ----
        {
            int wid = bid * 4 + (tid >> 6);
            int lane = tid & 63;
            int g = lane >> 5;
            int c = lane & 31;

            const _Float16* Wea_l = Weh + (size_t)l * 2048;
            half2_t w2[8][4];
            {
                const _Float16* wp = Wea_l + c * 64;
#pragma unroll
                for (int kp = 0; kp < 8; kp++) {
                    half8_t wv = *(const half8_t*)(wp + kp * 8);
                    w2[kp][0] = half2_t{wv[0], wv[1]};
                    w2[kp][1] = half2_t{wv[2], wv[3]};
                    w2[kp][2] = half2_t{wv[4], wv[5]};
                    w2[kp][3] = half2_t{wv[6], wv[7]};
                }
            }
            float bev[4];
            {
                float4 bb = *(const float4*)(be + (size_t)l * D + 4 * c);
                bev[0] = bb.x; bev[1] = bb.y; bev[2] = bb.z; bev[3] = bb.w;
            }
            float epsv = 1.0f + eps[l];

            const char* easb = (const char*)ea_s;
            const char* xbb = (const char*)xc;
            int coff = c << 3;

            int nstart = wid * AGG_Q + (wid < AGG_R ? wid : AGG_R);
            int ncnt   = AGG_Q + (wid < AGG_R ? 1 : 0);
            int nend   = nstart + ncnt;

            int tcur = __builtin_amdgcn_readfirstlane(off[nstart]);
            for (int n = nstart; n < nend; ++n) {
                float acc[4] = {0.f, 0.f, 0.f, 0.f};
                int t0 = tcur;
                int t1 = __builtin_amdgcn_readfirstlane(off[n + 1]);
                tcur = t1;

                auto process = [&](int te) {
                    int sx = sorted[te];
                    const char* ep = easb + ((size_t)te << 5);
                    half8_t elo = *(const half8_t*)ep;
                    half8_t ehi = *(const half8_t*)(ep + 16);
                    half4_t xv = *(const half4_t*)(xbb + sx + coff);
                    float p0 = bev[0], p1 = bev[1], p2 = bev[2], p3 = bev[3];
#pragma unroll
                    for (int kp = 0; kp < 4; kp++) {
                        half2_t e2 = half2_t{elo[2 * kp], elo[2 * kp + 1]};
                        p0 = FDOT2(e2, w2[kp][0], p0);
                        p1 = FDOT2(e2, w2[kp][1], p1);
                        p2 = FDOT2(e2, w2[kp][2], p2);
                        p3 = FDOT2(e2, w2[kp][3], p3);
                    }
#pragma unroll
                    for (int kp = 0; kp < 4; kp++) {
                        half2_t e2 = half2_t{ehi[2 * kp], ehi[2 * kp + 1]};
                        p0 = FDOT2(e2, w2[kp + 4][0], p0);
                        p1 = FDOT2(e2, w2[kp + 4][1], p1);
                        p2 = FDOT2(e2, w2[kp + 4][2], p2);
                        p3 = FDOT2(e2, w2[kp + 4][3], p3);
                    }
                    acc[0] += fmaxf((float)xv[0] + p0, 0.f);
                    acc[1] += fmaxf((float)xv[1] + p1, 0.f);
                    acc[2] += fmaxf((float)xv[2] + p2, 0.f);
                    acc[3] += fmaxf((float)xv[3] + p3, 0.f);
                };

                int t = t0;
                for (; t + 4 <= t1; t += 4) {
                    process(t + g);
                    process(t + g + 2);
                }
                for (; t < t1; t += 2) {
                    int te = t + g;
                    if (te < t1) process(te);
                }

#pragma unroll
                for (int f = 0; f < 4; f++) acc[f] += __shfl_xor(acc[f], 32, 64);

                if (g == 0) {
                    half4_t xv = *(const half4_t*)(xc + (size_t)n * D + 4 * c);
                    half4_t oh;
#pragma unroll
                    for (int f = 0; f < 4; f++)
                        oh[f] = (_Float16)(fmaf(epsv, (float)xv[f], acc[f]));
                    *(half4_t*)(h0 + (size_t)n * D + 4 * c) = oh;
                }
            }
        }
        gbar(gcnt, gflg, barix++);

        // ---- mlp (zero-barrier, A from global h0, 4-col halves) ----
        {
            int n0m = bid * 64;
            if (n0m < N_NODES) {
                _Float16* sG = (_Float16*)smem;
                int w = tid >> 6, lane = tid & 63, q = lane >> 4, r16 = lane & 15;
                int mrow = w * 16 + r16;
                int grow = n0m + mrow;
                int growc = grow < N_NODES ? grow : N_NODES - 1;
                const _Float16* hrow = h0 + (size_t)growc * D;
                const _Float16* W1p = Wp + (size_t)(2 * l) * 16384;
                const _Float16* W2p = Wp + (size_t)(2 * l + 1) * 16384;
                const float* b1l = b1 + (size_t)l * D;
                const float* b2l = b2 + (size_t)l * D;

                half8_t av[4];
#pragma unroll
                for (int kb = 0; kb < 4; kb++)
                    av[kb] = *(const half8_t*)(hrow + kb * 32 + q * 8);

#pragma unroll
                for (int hh = 0; hh < 2; hh++) {
                    floatx4 acc[4];
#pragma unroll
                    for (int j = 0; j < 4; j++) acc[j] = floatx4{0.f, 0.f, 0.f, 0.f};
#pragma unroll
                    for (int kb = 0; kb < 4; kb++) {
#pragma unroll
                        for (int j = 0; j < 4; j++) {
                            int nb = hh * 4 + j;
                            half8_t bv = *(const half8_t*)(W1p + (size_t)((kb * 8 + nb) * 64 + lane) * 8);
                            acc[j] = __builtin_amdgcn_mfma_f32_16x16x32_f16(av[kb], bv, acc[j], 0, 0, 0);
                        }
                    }
#pragma unroll
                    for (int j = 0; j < 4; j++) {
                        int col = (hh * 4 + j) * 16 + r16;
                        float bb = b1l[col];
#pragma unroll
                        for (int r = 0; r < 4; r++) {
                            float v = acc[j][r] + bb;
                            float gl = 0.5f * v * (1.0f + erff(v * 0.70710678118654752f));
                            sG[(w * 16 + q * 4 + r) * 136 + col] = (_Float16)gl;
                        }
                    }
                }
                // wave w wrote exactly the sG rows it reads — no barrier
                half8_t gv[4];
#pragma unroll
                for (int kb = 0; kb < 4; kb++)
                    gv[kb] = *(const half8_t*)&sG[mrow * 136 + kb * 32 + q * 8];

#pragma unroll
                for (int hh = 0; hh < 2; hh++) {
                    floatx4 acc[4];
#pragma unroll
                    for (int j = 0; j < 4; j++) acc[j] = floatx4{0.f, 0.f, 0.f, 0.f};
#pragma unroll
                    for (int kb = 0; kb < 4; kb++) {
#pragma unroll
                        for (int j = 0; j < 4; j++) {
                            int nb = hh * 4 + j;
                            half8_t bv = *(const half8_t*)(W2p + (size_t)((kb * 8 + nb) * 64 + lane) * 8);
                            acc[j] = __builtin_amdgcn_mfma_f32_16x16x32_f16(gv[kb], bv, acc[j], 0, 0, 0);
                        }
                    }
#pragma unroll
                    for (int j = 0; j < 4; j++) {
                        int col = (hh * 4 + j) * 16 + r16;
                        float bb = b2l[col];
#pragma unroll
                        for (int r = 0; r < 4; r++) {
                            int n = n0m + w * 16 + q * 4 + r;
                            if (n < N_NODES) {
                                float v = acc[j][r] + bb;
                                if (l == DEPTH - 1)
                                    __builtin_nontemporal_store(v, &outf[(size_t)n * D + col]);
                                else
                                    xn[(size_t)n * D + col] = (_Float16)v;
                            }
                        }
                    }
                }
            }
        }
        if (l < DEPTH - 1) {
            gbar(gcnt, gflg, barix++);
            _Float16* tmp = xc; xc = xn; xn = tmp;
        }
    }
}

// ---------------- launch ----------------

static inline size_t align_up(size_t v, size_t a) { return (v + a - 1) & ~(a - 1); }

extern "C" void kernel_launch(void* const* d_in, const int* in_sizes, int n_in,
                              void* d_out, int out_size, void* d_ws, size_t ws_size,
                              hipStream_t stream) {
    const float* x         = (const float*)d_in[0];
    const float* edge_attr = (const float*)d_in[1];
    const float* W1        = (const float*)d_in[2];
    const float* b1        = (const float*)d_in[3];
    const float* W2        = (const float*)d_in[4];
    const float* b2        = (const float*)d_in[5];
    const float* We        = (const float*)d_in[6];
    const float* be        = (const float*)d_in[7];
    const float* eps       = (const float*)d_in[8];
    const int*   src       = (const int*)d_in[9];
    const int*   dst       = ((const int*)d_in[9]) + N_EDGES;

    char* w = (char*)d_ws;
    int*  off    = (int*)w;  w += align_up((N_NODES + 1) * sizeof(int), 16);
    // zeroed region: deg + bflag + gcnt + gflg (contiguous, one memset)
    int*  deg    = (int*)w;  w += N_NODES * sizeof(int);
    int*  bflag  = (int*)w;  w += 64 * sizeof(int);
    unsigned* gcnt = (unsigned*)w; w += 16 * sizeof(unsigned);
    unsigned* gflg = (unsigned*)w; w += 16 * sizeof(unsigned);
    int*  head   = (int*)w;  w += align_up(N_NODES * sizeof(int), 16);
    int*  bsum   = (int*)w;  w += 64 * sizeof(int);
    int*  sorted = (int*)w;  w += align_up((size_t)N_EDGES * sizeof(int), 16);
    _Float16* xb0 = (_Float16*)w; w += (size_t)N_NODES * D * 2;
    _Float16* xb1 = (_Float16*)w; w += (size_t)N_NODES * D * 2;
    _Float16* h0b = (_Float16*)w; w += (size_t)N_NODES * D * 2;
    _Float16* ea_s = (_Float16*)w; w += (size_t)N_EDGES * E_DIM * 2 + 1024;
    _Float16* Wp  = (_Float16*)w; w += (size_t)6 * 16384 * 2;
    _Float16* Weh = (_Float16*)w; w += (size_t)3 * 2048 * 2;

    // ---- 3 dispatches total ----
    hipMemsetAsync(deg, 0, (N_NODES + 64 + 32) * sizeof(int), stream);
    k_prep<<<NB_PRE + NB_H, 256, 0, stream>>>(
        x, W1, W2, We, dst, xb0, Wp, Weh, deg);
    k_mega<<<GRID_BLOCKS, 256, 0, stream>>>(
        deg, off, head, bsum, bflag,
        src, dst, sorted, edge_attr, ea_s,
        xb0, xb1, h0b,
        Weh, be, eps, Wp, b1, b2, (float*)d_out,
        gcnt, gflg);
}

// Round 11
// 513.546 us; speedup vs baseline: 8.1977x; 8.1977x over previous
//
#include <hip/hip_runtime.h>
#include <math.h>

#define N_NODES 50000
#define N_EDGES 800000
#define D 128
#define E_DIM 16
#define DEPTH 3

typedef _Float16 half2_t __attribute__((ext_vector_type(2)));
typedef _Float16 half4_t __attribute__((ext_vector_type(4)));
typedef _Float16 half8_t __attribute__((ext_vector_type(8)));
typedef float floatx4 __attribute__((ext_vector_type(4)));

#if defined(__has_builtin)
#if __has_builtin(__builtin_amdgcn_fdot2)
#define FDOT2(a, b, c) __builtin_amdgcn_fdot2((a), (b), (c), false)
#endif
#endif
#ifndef FDOT2
static __device__ __forceinline__ float fdot2_sw(half2_t a, half2_t b, float c) {
    return fmaf((float)a.x, (float)b.x, fmaf((float)a.y, (float)b.y, c));
}
#define FDOT2(a, b, c) fdot2_sw((a), (b), (c))
#endif

// ---------------- CSR scan: one kernel, decoupled lookback (r8/r9-proven) ----
#define SCAN_BLOCKS 49   // ceil(N_NODES/1024)

__global__ __launch_bounds__(256) void k_scan(
    const int* __restrict__ deg, int* __restrict__ off, int* __restrict__ head,
    int* __restrict__ bsum, int* __restrict__ bflag) {
    __shared__ int s[256];
    int t = threadIdx.x;
    int base = blockIdx.x * 1024;
    int v[4]; int runv[4];
    int sum = 0;
#pragma unroll
    for (int j = 0; j < 4; j++) {
        int idx = base + t * 4 + j;
        int x = (idx < N_NODES) ? deg[idx] : 0;
        v[j] = x; sum += x;
    }
    s[t] = sum;
    __syncthreads();
    for (int d2 = 1; d2 < 256; d2 <<= 1) {
        int val = (t >= d2) ? s[t - d2] : 0;
        __syncthreads();
        s[t] += val;
        __syncthreads();
    }
    int run = (t > 0) ? s[t - 1] : 0;
#pragma unroll
    for (int j = 0; j < 4; j++) { run += v[j]; runv[j] = run; }
    if (t == 0) {
        atomicExch(&bsum[blockIdx.x], s[255]);
        __threadfence();
        atomicExch(&bflag[blockIdx.x], 1);
    }
    int p = 0;
    if (t < blockIdx.x) {
        while (atomicAdd(&bflag[t], 0) == 0) {}
        p = atomicAdd(&bsum[t], 0);
    }
    __syncthreads();            // s[] reuse
    s[t] = p;
    __syncthreads();
    for (int d2 = 128; d2 > 0; d2 >>= 1) {
        if (t < d2) s[t] += s[t + d2];
        __syncthreads();
    }
    int prefix = s[0];
    if (blockIdx.x == 0 && t == 0) off[0] = 0;
#pragma unroll
    for (int j = 0; j < 4; j++) {
        int idx = base + t * 4 + j;
        if (idx < N_NODES) {
            int incl = runv[j] + prefix;
            off[idx + 1] = incl;
            head[idx] = incl - v[j];   // exclusive prefix = scatter start
        }
    }
}

// sorted entries carry BYTE offsets: x-row byte off (src*256), e-attr byte off (e*32)
__global__ void k_scatter(const int* __restrict__ src, const int* __restrict__ dst,
                          int* __restrict__ head, int2* __restrict__ sorted) {
    int e = blockIdx.x * blockDim.x + threadIdx.x;
    if (e < N_EDGES) {
        int d = dst[e];
        int pos = atomicAdd(&head[d], 1);
        sorted[pos] = make_int2(src[e] << 8, e << 5);
    }
}

// ------- prep: f16 converts + MFMA weight packing + We packing + dst hist ----
// hist merged in (r5/r6-proven): independent work, atomic latency hides under
// the streaming converts; one fewer launch.

#define NB_X   3125    // N_NODES*D/8/256
#define NB_EA  6250    // N_EDGES*E_DIM/8/256
#define NB_W   384     // 6*16384/256
#define NB_WE  12      // 3*1024 half2 / 256
#define NB_H   3125    // N_EDGES/256
#define NB_PRE (NB_X + NB_EA + NB_W + NB_WE)

__global__ void k_prep(const float* __restrict__ x, const float* __restrict__ ea,
                       const float* __restrict__ W1, const float* __restrict__ W2,
                       const float* __restrict__ WeAll, const int* __restrict__ dst,
                       _Float16* __restrict__ xh, _Float16* __restrict__ eah,
                       _Float16* __restrict__ Wp, _Float16* __restrict__ Weh,
                       int* __restrict__ deg) {
    int b = blockIdx.x;
    if (b < NB_X + NB_EA) {
        const float* in = (b < NB_X) ? x : ea;
        _Float16* out = (b < NB_X) ? xh : eah;
        int i = (b < NB_X) ? (b * 256 + threadIdx.x) : ((b - NB_X) * 256 + threadIdx.x);
        int base = i * 8;
        float4 a = *(const float4*)(in + base);
        float4 c = *(const float4*)(in + base + 4);
        half8_t h = {(_Float16)a.x, (_Float16)a.y, (_Float16)a.z, (_Float16)a.w,
                     (_Float16)c.x, (_Float16)c.y, (_Float16)c.z, (_Float16)c.w};
        *(half8_t*)(out + base) = h;
    } else if (b < NB_X + NB_EA + NB_W) {
        int t = (b - NB_X - NB_EA) * 256 + threadIdx.x;
        int j    = t & 7;
        int lane = (t >> 3) & 63;
        int nb   = (t >> 9) & 7;
        int kb   = (t >> 12) & 3;
        int mat  = t >> 14;
        int layer = mat >> 1, which = mat & 1;
        const float* Wsrc = (which ? W2 : W1) + (size_t)layer * D * D;
        int k = kb * 32 + (lane >> 4) * 8 + j;
        int n = nb * 16 + (lane & 15);
        Wp[t] = (_Float16)Wsrc[k * D + n];
    } else if (b < NB_PRE) {
        // pack We as half2 pairs in k: layout [layer][c=0..31][kp=0..7][f=0..3]
        int t = (b - NB_X - NB_EA - NB_W) * 256 + threadIdx.x;  // 0..3071
        int layer = t >> 10;
        int idx = t & 1023;
        int c = idx >> 5, kp = (idx >> 2) & 7, f = idx & 3;
        const float* Wsrc = WeAll + (size_t)layer * E_DIM * D;
        half2_t v = {(_Float16)Wsrc[(2 * kp) * D + 4 * c + f],
                     (_Float16)Wsrc[(2 * kp + 1) * D + 4 * c + f]};
        *(half2_t*)(Weh + 2 * (size_t)t) = v;
    } else {
        int e = (b - NB_PRE) * 256 + threadIdx.x;
        if (e < N_EDGES) atomicAdd(&deg[dst[e]], 1);
    }
}

// ---------------- per-layer: aggregation (r3-verified, 79us) ----------------
// Persistent waves, 6 blocks/CU (grid 1536), contiguous balanced node ranges,
// unroll-2 per 32-lane group (4 gather chains/wave — the compiler's sustained
// max from HIP source, proven r1/r4/r5). This structure sits at the chip's
// random-line request floor (~3.2M lines/dispatch); r6 (fewer bytes), r7
// (DMA pipeline), r9 (nt hints), r10 (grid fusion) all failed to beat it.

#define AGG_BLOCKS 1536
#define AGG_WAVES  (AGG_BLOCKS * 4)   // 6144
#define AGG_Q      (N_NODES / AGG_WAVES)          // 8
#define AGG_R      (N_NODES - AGG_Q * AGG_WAVES)  // 848

__global__ __launch_bounds__(256, 6) void k_agg(
    const _Float16* __restrict__ xb, const _Float16* __restrict__ eah,
    const int2* __restrict__ sorted, const int* __restrict__ off,
    const _Float16* __restrict__ Wea_l, const float* __restrict__ be_l,
    const float* __restrict__ eps_ptr, _Float16* __restrict__ h0) {
    int wid = blockIdx.x * 4 + (threadIdx.x >> 6);
    int lane = threadIdx.x & 63;
    int g = lane >> 5;        // group 0/1
    int c = lane & 31;        // feature slice: feats 4c..4c+3

    // pre-packed We pairs: 64 contiguous halfs per lane, vector loads, no cvt
    half2_t w2[8][4];
    {
        const _Float16* wp = Wea_l + c * 64;
#pragma unroll
        for (int kp = 0; kp < 8; kp++) {
            half8_t wv = *(const half8_t*)(wp + kp * 8);
            w2[kp][0] = half2_t{wv[0], wv[1]};
            w2[kp][1] = half2_t{wv[2], wv[3]};
            w2[kp][2] = half2_t{wv[4], wv[5]};
            w2[kp][3] = half2_t{wv[6], wv[7]};
        }
    }
    float bev[4];
    {
        float4 bb = *(const float4*)(be_l + 4 * c);
        bev[0] = bb.x; bev[1] = bb.y; bev[2] = bb.z; bev[3] = bb.w;
    }
    float epsv = 1.0f + eps_ptr[0];

    const char* eab = (const char*)eah;
    const char* xbb = (const char*)xb;
    int coff = c << 3;

    // balanced contiguous partition: wave wid -> [nstart, nstart+ncnt)
    int nstart = wid * AGG_Q + (wid < AGG_R ? wid : AGG_R);
    int ncnt   = AGG_Q + (wid < AGG_R ? 1 : 0);
    int nend   = nstart + ncnt;

    int tcur = __builtin_amdgcn_readfirstlane(off[nstart]);
    for (int n = nstart; n < nend; ++n) {
        float acc[4] = {0.f, 0.f, 0.f, 0.f};
        int t0 = tcur;
        int t1 = __builtin_amdgcn_readfirstlane(off[n + 1]);
        tcur = t1;

        auto process = [&](int te) {
            int2 se = sorted[te];
            const char* ep = eab + se.y;
            half8_t elo = *(const half8_t*)ep;
            half8_t ehi = *(const half8_t*)(ep + 16);
            half4_t xv = *(const half4_t*)(xbb + se.x + coff);
            float p0 = bev[0], p1 = bev[1], p2 = bev[2], p3 = bev[3];
#pragma unroll
            for (int kp = 0; kp < 4; kp++) {
                half2_t e2 = half2_t{elo[2 * kp], elo[2 * kp + 1]};
                p0 = FDOT2(e2, w2[kp][0], p0);
                p1 = FDOT2(e2, w2[kp][1], p1);
                p2 = FDOT2(e2, w2[kp][2], p2);
                p3 = FDOT2(e2, w2[kp][3], p3);
            }
#pragma unroll
            for (int kp = 0; kp < 4; kp++) {
                half2_t e2 = half2_t{ehi[2 * kp], ehi[2 * kp + 1]};
                p0 = FDOT2(e2, w2[kp + 4][0], p0);
                p1 = FDOT2(e2, w2[kp + 4][1], p1);
                p2 = FDOT2(e2, w2[kp + 4][2], p2);
                p3 = FDOT2(e2, w2[kp + 4][3], p3);
            }
            acc[0] += fmaxf((float)xv[0] + p0, 0.f);
            acc[1] += fmaxf((float)xv[1] + p1, 0.f);
            acc[2] += fmaxf((float)xv[2] + p2, 0.f);
            acc[3] += fmaxf((float)xv[3] + p3, 0.f);
        };

        int t = t0;
        for (; t + 4 <= t1; t += 4) {      // both groups, 2 slots each
            process(t + g);
            process(t + g + 2);
        }
        for (; t < t1; t += 2) {           // remainder (<=3 edges)
            int te = t + g;
            if (te < t1) process(te);
        }

        // cross-group reduction: lane l += lane l^32
#pragma unroll
        for (int f = 0; f < 4; f++) acc[f] += __shfl_xor(acc[f], 32, 64);

        if (g == 0) {
            half4_t xv = *(const half4_t*)(xb + (size_t)n * D + 4 * c);
            half4_t oh;
#pragma unroll
            for (int f = 0; f < 4; f++)
                oh[f] = (_Float16)(fmaf(epsv, (float)xv[f], acc[f]));
            *(half4_t*)(h0 + (size_t)n * D + 4 * c) = oh;
        }
    }
}

// ---------------- per-layer: fused node MLP via MFMA f16 (r0-r6-proven) -----

template <bool LAST>
__global__ __launch_bounds__(256) void k_mlp(
    const _Float16* __restrict__ h0, const _Float16* __restrict__ W1p,
    const float* __restrict__ b1, const _Float16* __restrict__ W2p,
    const float* __restrict__ b2, float* __restrict__ outf,
    _Float16* __restrict__ outh) {
    __shared__ _Float16 sH[64 * 136];
    __shared__ _Float16 sG[64 * 136];
    int n0 = blockIdx.x * 64;
    int t = threadIdx.x;

    for (int cc = t; cc < 1024; cc += 256) {
        int row = cc >> 4, c4 = cc & 15;
        uint4 v = make_uint4(0, 0, 0, 0);
        if (n0 + row < N_NODES)
            v = *(const uint4*)(h0 + (size_t)(n0 + row) * D + c4 * 8);
        *(uint4*)&sH[row * 136 + c4 * 8] = v;
    }
    __syncthreads();

    int w = t >> 6, lane = t & 63, q = lane >> 4, r16 = lane & 15;
    int mrow = w * 16 + r16;

    floatx4 acc[8];
#pragma unroll
    for (int nb = 0; nb < 8; nb++) acc[nb] = floatx4{0.f, 0.f, 0.f, 0.f};
#pragma unroll
    for (int kb = 0; kb < 4; kb++) {
        half8_t av = *(const half8_t*)&sH[mrow * 136 + kb * 32 + q * 8];
#pragma unroll
        for (int nb = 0; nb < 8; nb++) {
            half8_t bv = *(const half8_t*)(W1p + (size_t)((kb * 8 + nb) * 64 + lane) * 8);
            acc[nb] = __builtin_amdgcn_mfma_f32_16x16x32_f16(av, bv, acc[nb], 0, 0, 0);
        }
    }
#pragma unroll
    for (int nb = 0; nb < 8; nb++) {
        int col = nb * 16 + r16;
        float bb = b1[col];
#pragma unroll
        for (int r = 0; r < 4; r++) {
            float v = acc[nb][r] + bb;
            float gl = 0.5f * v * (1.0f + erff(v * 0.70710678118654752f));
            sG[(w * 16 + q * 4 + r) * 136 + col] = (_Float16)gl;
        }
    }
    // wave w writes exactly the sG rows it reads below — no barrier needed

#pragma unroll
    for (int nb = 0; nb < 8; nb++) acc[nb] = floatx4{0.f, 0.f, 0.f, 0.f};
#pragma unroll
    for (int kb = 0; kb < 4; kb++) {
        half8_t av = *(const half8_t*)&sG[mrow * 136 + kb * 32 + q * 8];
#pragma unroll
        for (int nb = 0; nb < 8; nb++) {
            half8_t bv = *(const half8_t*)(W2p + (size_t)((kb * 8 + nb) * 64 + lane) * 8);
            acc[nb] = __builtin_amdgcn_mfma_f32_16x16x32_f16(av, bv, acc[nb], 0, 0, 0);
        }
    }
#pragma unroll
    for (int nb = 0; nb < 8; nb++) {
        int col = nb * 16 + r16;
        float bb = b2[col];
#pragma unroll
        for (int r = 0; r < 4; r++) {
            int n = n0 + w * 16 + q * 4 + r;
            if (n < N_NODES) {
                float v = acc[nb][r] + bb;
                if (LAST) outf[(size_t)n * D + col] = v;
                else      outh[(size_t)n * D + col] = (_Float16)v;
            }
        }
    }
}

// ---------------- launch ----------------

static inline size_t align_up(size_t v, size_t a) { return (v + a - 1) & ~(a - 1); }

extern "C" void kernel_launch(void* const* d_in, const int* in_sizes, int n_in,
                              void* d_out, int out_size, void* d_ws, size_t ws_size,
                              hipStream_t stream) {
    const float* x         = (const float*)d_in[0];
    const float* edge_attr = (const float*)d_in[1];
    const float* W1        = (const float*)d_in[2];
    const float* b1        = (const float*)d_in[3];
    const float* W2        = (const float*)d_in[4];
    const float* b2        = (const float*)d_in[5];
    const float* We        = (const float*)d_in[6];
    const float* be        = (const float*)d_in[7];
    const float* eps       = (const float*)d_in[8];
    const int*   src       = (const int*)d_in[9];
    const int*   dst       = ((const int*)d_in[9]) + N_EDGES;

    char* w = (char*)d_ws;
    int*  off    = (int*)w;  w += align_up((N_NODES + 1) * sizeof(int), 16);
    int*  deg    = (int*)w;  w += N_NODES * sizeof(int);   // deg + bflag contiguous
    int*  bflag  = (int*)w;  w += 64 * sizeof(int);        // (one memset covers both)
    int*  head   = (int*)w;  w += align_up(N_NODES * sizeof(int), 16);
    int*  bsum   = (int*)w;  w += 64 * sizeof(int);
    int2* sorted = (int2*)w; w += (size_t)N_EDGES * sizeof(int2);
    _Float16* xb0 = (_Float16*)w; w += (size_t)N_NODES * D * 2;
    _Float16* xb1 = (_Float16*)w; w += (size_t)N_NODES * D * 2;
    _Float16* h0b = (_Float16*)w; w += (size_t)N_NODES * D * 2;
    _Float16* eah = (_Float16*)w; w += (size_t)N_EDGES * E_DIM * 2;
    _Float16* Wp  = (_Float16*)w; w += (size_t)6 * 16384 * 2;
    _Float16* Weh = (_Float16*)w; w += (size_t)3 * 2048 * 2;

    // ---- CSR build + prep: 4 dispatches ----
    hipMemsetAsync(deg, 0, (N_NODES + 64) * sizeof(int), stream);   // deg + bflag
    k_prep<<<NB_PRE + NB_H, 256, 0, stream>>>(
        x, edge_attr, W1, W2, We, dst, xb0, eah, Wp, Weh, deg);
    k_scan<<<SCAN_BLOCKS, 256, 0, stream>>>(deg, off, head, bsum, bflag);
    k_scatter<<<(N_EDGES + 255) / 256, 256, 0, stream>>>(src, dst, head, sorted);

    // ---- 3 layers ----
    _Float16* xcur = xb0;
    _Float16* xnxt = xb1;
    for (int l = 0; l < DEPTH; l++) {
        k_agg<<<AGG_BLOCKS, 256, 0, stream>>>(
            xcur, eah, sorted, off,
            Weh + (size_t)l * 2048, be + (size_t)l * D, eps + l, h0b);
        const _Float16* W1p = Wp + (size_t)(l * 2 + 0) * 16384;
        const _Float16* W2p = Wp + (size_t)(l * 2 + 1) * 16384;
        if (l == DEPTH - 1) {
            k_mlp<true><<<(N_NODES + 63) / 64, 256, 0, stream>>>(
                h0b, W1p, b1 + (size_t)l * D, W2p, b2 + (size_t)l * D,
                (float*)d_out, nullptr);
        } else {
            k_mlp<false><<<(N_NODES + 63) / 64, 256, 0, stream>>>(
                h0b, W1p, b1 + (size_t)l * D, W2p, b2 + (size_t)l * D,
                nullptr, xnxt);
        }
        _Float16* tmp = xcur; xcur = xnxt; xnxt = tmp;
    }
}